// Round 6
// baseline (150.282 us; speedup 1.0000x reference)
//
#include <hip/hip_runtime.h>

// xDeepFM CIN, MI355X (gfx950) — R15: batch-quad waves in cin_h.
// R14 post-mortem: VALUBusy 37->26 as designed but cin_h 55->61.5us,
// MfmaUtil 43->38: VALU never serialized the matrix pipe; doubling W-frag
// loads/wave (and L1 footprint) was the regression. R11+R14 agree: the
// W-load path is binding; winning direction = more MFMAs per W-load.
// R15: wave = (g, quad of 4 batches). Per j: 2 W-frag loads feed 16 MFMAs
// (4 b x 2 nh x 2 kq) — W/MFMA halves vs R10, refill window ~512 cyc >>
// L2 latency. kq-outer MFMA order spaces same-acc pairs 8 apart.
// Block = 8 batches / 256 thr / grid 256 (1 block/CU). ~330 unified regs
// @ launch_bounds(256,1). LDS 73.7KB. p-chunks 2 batches/wave.
// prep_frag, R13 frag-ordered pW, cin_out: unchanged.

typedef _Float16 f16;
typedef _Float16 f16x4 __attribute__((ext_vector_type(4)));
typedef _Float16 f16x8 __attribute__((ext_vector_type(8)));
typedef float f32x4 __attribute__((ext_vector_type(4)));
typedef float f32x16 __attribute__((ext_vector_type(16)));

#define HSTR 72      // h LDS row stride (f16): 144B = 9*16B, b128-aligned
#define GSTR 163840  // pW per-32-batch-group stride (f16): 320 frags * 512
#define P0G  0       // p0 frags [0,64)   within group
#define P1G  32768   // p1 frags [0,128)  within group
#define P2G  98304   // p2 frags [0,128)  within group

__device__ __forceinline__ f32x16 zero16() {
    f32x16 v;
#pragma unroll
    for (int i = 0; i < 16; ++i) v[i] = 0.0f;
    return v;
}

// ---------------- prep: W (fp32 row-major) -> f16 fragment-ordered ----------
// Fragment (mc, kk) = 512 f16; element lane*8+i =
//   W[rbase + mc*32 + (lane&31)][kk*16 + (lane>>5)*8 + i]
// Regions (f16 offsets): H0@0 (W0 r0..63, KK=64) | O0@65536 (W0 r64..127) |
// H1@131072 (W1 r0..63, KK=128) | O1@262144 (W1 r64..127) | O2@393216 (W2 all).
__global__ void __launch_bounds__(256)
prep_frag(const float* __restrict__ W0, const float* __restrict__ W1,
          const float* __restrict__ W2, f16* __restrict__ dst)
{
    int g = (blockIdx.x * 256 + threadIdx.x) * 8;    // grid = 320
    const float* src; int base, KK, rbase;
    if (g < 65536)       { src = W0; base = 0;      KK = 64;  rbase = 0;  }
    else if (g < 131072) { src = W0; base = 65536;  KK = 64;  rbase = 64; }
    else if (g < 262144) { src = W1; base = 131072; KK = 128; rbase = 0;  }
    else if (g < 393216) { src = W1; base = 262144; KK = 128; rbase = 64; }
    else                 { src = W2; base = 393216; KK = 128; rbase = 0;  }
    int local = g - base;
    int frag  = local >> 9;
    int lane  = (local >> 3) & 63;
    int kk    = frag % KK;
    int mc    = frag / KK;
    int row   = rbase + mc * 32 + (lane & 31);
    int col   = kk * 16 + (lane >> 5) * 8;
    int IC    = KK * 16;
    const float* s = src + (size_t)row * IC + col;
    f16x8 o;
#pragma unroll
    for (int i = 0; i < 8; ++i) o[i] = (f16)s[i];
    *(f16x8*)(dst + g) = o;
}

// ---- p-chunk: P rows [jb, jb+32) of one batch (M=32 j, N=32 z, K=64) ------
// Writes fragment-ordered: pdst = groupbase + regionoff + (b&31)*8.
__device__ __forceinline__ void p_chunk(const f16* __restrict__ hrows,
                                        const f16x8 (&pB)[4],
                                        f16* __restrict__ pdst, int jb,
                                        int t, int q)
{
    f32x16 acc = zero16();
#pragma unroll
    for (int s = 0; s < 4; ++s) {
        f16x8 a = *(const f16x8*)(hrows + t * HSTR + s * 16 + q * 8);
        acc = __builtin_amdgcn_mfma_f32_32x32x16_f16(a, pB[s], acc, 0, 0, 0);
    }
#pragma unroll
    for (int r = 0; r < 16; ++r) {
        int j = jb + (r & 3) + 8 * (r >> 2) + 4 * q;
        int f = j * 2 + (t >> 4);
        pdst[f * 512 + ((t >> 3) & 1) * 256 + (t & 7)] = (f16)acc[r];
    }
}

// ---- h-GEMM (R15): wave = (g, quad): rows [g*32,+32), all 64 cols, 4 batches
// Per j: 2 W-frag loads + 8 LDS scalar reads feed 16 MFMAs (~512 SIMD-cyc).
// Ping-pong depth-2 (j, j+1 resident; refill j+2). kq-outer MFMA order.
template <int HJ>
__device__ __forceinline__ void h_gemm_quad(const f16* __restrict__ Hf,
                                            const f16* const (&hp)[4],
                                            int lane8, int t,
                                            const f16x8 (&ip)[4][2][2], // [b][kq][nh]
                                            f32x16 (&acc)[4][2])        // [b][nh]
{
#pragma unroll
    for (int b = 0; b < 4; ++b) { acc[b][0] = zero16(); acc[b][1] = zero16(); }
    const f16* Wp = Hf + lane8;
    f16x8 wf[2][2];      // [phase][kq]
    f16   sc[2][4][2];   // [phase][b][nh]
#pragma unroll
    for (int ph = 0; ph < 2; ++ph) {
        wf[ph][0] = *(const f16x8*)(Wp + (ph * 2 + 0) * 512);
        wf[ph][1] = *(const f16x8*)(Wp + (ph * 2 + 1) * 512);
#pragma unroll
        for (int b = 0; b < 4; ++b) {
            sc[ph][b][0] = hp[b][ph * HSTR + t];
            sc[ph][b][1] = hp[b][ph * HSTR + 32 + t];
        }
    }
    for (int jj = 0; jj < HJ; jj += 2) {
#pragma unroll
        for (int ph = 0; ph < 2; ++ph) {
            f16x8 w0 = wf[ph][0], w1 = wf[ph][1];
            f16 s[4][2];
#pragma unroll
            for (int b = 0; b < 4; ++b) {
                s[b][0] = sc[ph][b][0];
                s[b][1] = sc[ph][b][1];
            }
            int jn = jj + ph + 2;
            if (jn > HJ - 1) jn = HJ - 1;              // clamped refill
            wf[ph][0] = *(const f16x8*)(Wp + (jn * 2 + 0) * 512);
            wf[ph][1] = *(const f16x8*)(Wp + (jn * 2 + 1) * 512);
#pragma unroll
            for (int b = 0; b < 4; ++b) {
                sc[ph][b][0] = hp[b][jn * HSTR + t];
                sc[ph][b][1] = hp[b][jn * HSTR + 32 + t];
            }
            // kq = 0 products + MFMAs (8 distinct accs)
            f16x8 pr0[4][2];
#pragma unroll
            for (int b = 0; b < 4; ++b) {
                pr0[b][0] = ip[b][0][0] * s[b][0];
                pr0[b][1] = ip[b][0][1] * s[b][1];
            }
#pragma unroll
            for (int b = 0; b < 4; ++b) {
                acc[b][0] = __builtin_amdgcn_mfma_f32_32x32x16_f16(w0, pr0[b][0], acc[b][0], 0, 0, 0);
                acc[b][1] = __builtin_amdgcn_mfma_f32_32x32x16_f16(w0, pr0[b][1], acc[b][1], 0, 0, 0);
            }
            // kq = 1 products + MFMAs (same accs, 8-apart spacing)
            f16x8 pr1[4][2];
#pragma unroll
            for (int b = 0; b < 4; ++b) {
                pr1[b][0] = ip[b][1][0] * s[b][0];
                pr1[b][1] = ip[b][1][1] * s[b][1];
            }
#pragma unroll
            for (int b = 0; b < 4; ++b) {
                acc[b][0] = __builtin_amdgcn_mfma_f32_32x32x16_f16(w1, pr1[b][0], acc[b][0], 0, 0, 0);
                acc[b][1] = __builtin_amdgcn_mfma_f32_32x32x16_f16(w1, pr1[b][1], acc[b][1], 0, 0, 0);
            }
        }
    }
}

__device__ __forceinline__ void load_bias(const float* __restrict__ bl,
                                          float (&bve)[16], int g, int q)
{
#pragma unroll
    for (int r = 0; r < 16; ++r)
        bve[r] = bl[g * 32 + (r & 3) + 8 * (r >> 2) + 4 * q];
}

// Write h_{l+1} rows [g*32,+32), all 64 cols, 4 batches.
__device__ __forceinline__ void epi_quad(const f32x16 (&acc)[4][2],
                                         f16* const (&hp)[4],
                                         const float (&bve)[16],
                                         int g, int t, int q)
{
#pragma unroll
    for (int r = 0; r < 16; ++r) {
        int row = g * 32 + (r & 3) + 8 * (r >> 2) + 4 * q;
#pragma unroll
        for (int b = 0; b < 4; ++b) {
            hp[b][row * HSTR + t]      = (f16)(acc[b][0][r] + bve[r]);
            hp[b][row * HSTR + 32 + t] = (f16)(acc[b][1][r] + bve[r]);
        }
    }
}

// =================== Kernel 1: h-chain + p-vectors =========================
__global__ void __launch_bounds__(256, 1)
cin_h(const float* __restrict__ inp, const f16* __restrict__ Wf,
      f16* __restrict__ pW,
      const float* __restrict__ b0v, const float* __restrict__ b1v)
{
    __shared__ __attribute__((aligned(16))) f16 hL[8 * 64 * HSTR];  // 73728 B

    const int tid   = threadIdx.x;
    const int w     = tid >> 6;
    const int lane  = tid & 63;
    const int t     = lane & 31;
    const int q     = lane >> 5;
    const int lane8 = lane * 8;
    const int g     = w & 1;          // row-half
    const int quad  = w >> 1;         // batch-quad (local batches quad*4..+3)
    const int b0i   = blockIdx.x * 8;

    // Stage: 8 batches x 32 z-rows of inp (f32 coalesced) -> hL rows 0..31.
#pragma unroll
    for (int it = 0; it < 16; ++it) {
        int idx = it * 1024 + tid * 4;
        int b = idx >> 11, rem = idx & 2047;
        int z = rem >> 6, k = rem & 63;
        f32x4 v = *(const f32x4*)(inp + (size_t)(b0i + b) * 2048 + rem);
        f16x4 h4;
        h4[0] = (f16)v[0]; h4[1] = (f16)v[1]; h4[2] = (f16)v[2]; h4[3] = (f16)v[3];
        *(f16x4*)(hL + b * 64 * HSTR + z * HSTR + k) = h4;
    }
    __syncthreads();                                   // B0: h0 (=inp) ready

    // Wave's 4 GEMM batches.
    f16* hp[4];
#pragma unroll
    for (int b = 0; b < 4; ++b) hp[b] = hL + (quad * 4 + b) * 64 * HSTR;
    const f16* const (&hpc)[4] = (const f16* const (&)[4])hp;

    // ip[b][kq][nh][i] = inp[quad*4+b][z=kq*16+q*8+i][nh*32+t]
    f16x8 ip[4][2][2];
#pragma unroll
    for (int b = 0; b < 4; ++b) {
        const f16* src = hp[b];
#pragma unroll
        for (int kq = 0; kq < 2; ++kq)
#pragma unroll
            for (int nh = 0; nh < 2; ++nh) {
                f16x8 v;
#pragma unroll
                for (int i = 0; i < 8; ++i)
                    v[i] = src[(kq * 16 + q * 8 + i) * HSTR + nh * 32 + t];
                ip[b][kq][nh] = v;
            }
    }
    // p-work: wave w owns local batches {2w, 2w+1}.
    f16x8 pB[2][4];
#pragma unroll
    for (int lb = 0; lb < 2; ++lb)
#pragma unroll
        for (int s = 0; s < 4; ++s)
            pB[lb][s] = *(const f16x8*)(hL + (w * 2 + lb) * 64 * HSTR +
                                        t * HSTR + s * 16 + q * 8);
    const f16* hq0 = hL + (w * 2) * 64 * HSTR;
    const f16* hq1 = hL + (w * 2 + 1) * 64 * HSTR;
    const int bg0 = b0i + w * 2, bg1 = b0i + w * 2 + 1;
    f16* pG0 = pW + (size_t)(bg0 >> 5) * GSTR + (bg0 & 31) * 8;
    f16* pG1 = pW + (size_t)(bg1 >> 5) * GSTR + (bg1 & 31) * 8;

    const f16* H0 = Wf;
    const f16* H1 = Wf + 131072;
    f32x16 acc[4][2];
    float bve[16];

    // ---- Layer 0 (HJ=32) ----
    p_chunk(hq0, pB[0], pG0 + P0G, 0, t, q);           // p0 j 0..31
    p_chunk(hq1, pB[1], pG1 + P0G, 0, t, q);
    h_gemm_quad<32>(H0 + g * 64 * 512, hpc, lane8, t, ip, acc);
    load_bias(b0v, bve, g, q);
    __syncthreads();                                   // B1: all h0 reads done
    epi_quad(acc, hp, bve, g, t, q);                   // h1 (rows g*32..+32)
    __syncthreads();                                   // B2: h1 ready

    // ---- Layer 1 (HJ=64) ----
    p_chunk(hq0,             pB[0], pG0 + P1G, 0,  t, q);
    p_chunk(hq0 + 32 * HSTR, pB[0], pG0 + P1G, 32, t, q);
    p_chunk(hq1,             pB[1], pG1 + P1G, 0,  t, q);
    p_chunk(hq1 + 32 * HSTR, pB[1], pG1 + P1G, 32, t, q);
    h_gemm_quad<64>(H1 + g * 128 * 512, hpc, lane8, t, ip, acc);
    load_bias(b1v, bve, g, q);
    __syncthreads();                                   // B3: all h1 reads done
    epi_quad(acc, hp, bve, g, t, q);                   // h1 -> h2 in place
    __syncthreads();                                   // B4: h2 ready

    p_chunk(hq0,             pB[0], pG0 + P2G, 0,  t, q);
    p_chunk(hq0 + 32 * HSTR, pB[0], pG0 + P2G, 32, t, q);
    p_chunk(hq1,             pB[1], pG1 + P2G, 0,  t, q);
    p_chunk(hq1 + 32 * HSTR, pB[1], pG1 + P2G, 32, t, q);
}

// =================== Kernel 2: out GEMMs (N = batch), R13 ==================
// Block = 512 thr (8 waves): mi = M-half, ki = K-quarter. B-frags 1KB
// wave-coalesced (fragment-ordered pW); mi-pair reads identical addresses
// (L1 share). Depth-8 prefetch ring. 4-way K partials reduced via 32KB LDS.
template <int KK>   // KK = total K-fragments (region0: 64, others: 128)
__device__ __forceinline__ void o_tile(const f16* __restrict__ Of,
                                       const f16* __restrict__ pBase,
                                       const float* __restrict__ biasp,
                                       float* __restrict__ out,
                                       float* __restrict__ rP,
                                       int bg, int colbase, int tid)
{
    const int w = tid >> 6, lane = tid & 63, t = lane & 31, q = lane >> 5;
    const int lane8 = lane * 8;
    const int mi = w & 1, ki = w >> 1;           // mi pairs adjacent -> B share
    const int SQ = KK / 4;                       // K-frags per wave (16 or 32)
    const f16* Ap = Of + (size_t)(mi * KK + ki * SQ) * 512 + lane8;
    const f16* Bp = pBase + (size_t)(ki * SQ) * 512 + lane8;

    f32x16 acc = zero16();
    f16x8 af[8], bf[8];
#pragma unroll
    for (int i = 0; i < 8; ++i) {
        af[i] = *(const f16x8*)(Ap + i * 512);
        bf[i] = *(const f16x8*)(Bp + i * 512);
    }
#pragma unroll 8
    for (int s = 0; s < SQ; ++s) {
        int idx = s & 7;
        f16x8 a = af[idx], b = bf[idx];
        int sn = s + 8 < SQ ? s + 8 : SQ - 1;    // clamped refill
        af[idx] = *(const f16x8*)(Ap + sn * 512);
        bf[idx] = *(const f16x8*)(Bp + sn * 512);
        acc = __builtin_amdgcn_mfma_f32_32x32x16_f16(a, b, acc, 0, 0, 0);
    }
#pragma unroll
    for (int r = 0; r < 16; ++r) {
        int m = mi * 32 + (r & 3) + 8 * (r >> 2) + 4 * q;
        rP[(ki * 32 + t) * 64 + m] = acc[r];
    }
    __syncthreads();
    // Combine: 512 thr x f32x4 = 2048 f32 (32 batches x 64 cols).
    {
        int n = tid >> 4;            // batch row 0..31
        int o = (tid & 15) * 4;      // col 0..60
        f32x4 v = *(const f32x4*)(rP + n * 64 + o);
#pragma unroll
        for (int k2 = 1; k2 < 4; ++k2) {
            f32x4 u = *(const f32x4*)(rP + (k2 * 32 + n) * 64 + o);
            v[0] += u[0]; v[1] += u[1]; v[2] += u[2]; v[3] += u[3];
        }
        f32x4 bb = *(const f32x4*)(biasp + o);
        v[0] += 64.0f * bb[0]; v[1] += 64.0f * bb[1];
        v[2] += 64.0f * bb[2]; v[3] += 64.0f * bb[3];
        *(f32x4*)(out + (size_t)(bg * 32 + n) * 256 + colbase + o) = v;
    }
}

__global__ void __launch_bounds__(512, 2)
cin_out(const f16* __restrict__ Wf, const f16* __restrict__ pW,
        const float* __restrict__ b0v, const float* __restrict__ b1v,
        const float* __restrict__ b2v, float* __restrict__ out)
{
    __shared__ __attribute__((aligned(16))) float rP[4 * 32 * 64];  // 32 KB
    const int tid = threadIdx.x;
    const int r  = blockIdx.x & 3;      // region
    const int bg = blockIdx.x >> 2;     // 32-batch group (64 of them)
    const f16* pGrp = pW + (size_t)bg * GSTR;
    if (r == 0)
        o_tile<64> (Wf + 65536,  pGrp + P0G, b0v + 64, out, rP, bg, 0,   tid);
    else if (r == 1)
        o_tile<128>(Wf + 262144, pGrp + P1G, b1v + 64, out, rP, bg, 64,  tid);
    else if (r == 2)
        o_tile<128>(Wf + 393216, pGrp + P2G, b2v,      out, rP, bg, 128, tid);
    else
        o_tile<128>(Wf + 524288, pGrp + P2G, b2v + 64, out, rP, bg, 192, tid);
}

extern "C" void kernel_launch(void* const* d_in, const int* in_sizes, int n_in,
                              void* d_out, int out_size, void* d_ws, size_t ws_size,
                              hipStream_t stream)
{
    const float* inp = (const float*)d_in[0];
    const float* W0  = (const float*)d_in[1];
    const float* b0  = (const float*)d_in[2];
    const float* W1  = (const float*)d_in[3];
    const float* b1  = (const float*)d_in[4];
    const float* W2  = (const float*)d_in[5];
    const float* b2  = (const float*)d_in[6];
    float* out = (float*)d_out;

    f16* Wf = (f16*)d_ws;             // 655360 f16 = 1.25 MB fragment-ordered
    f16* pW = Wf + 655360;            // 64 groups * 163840 f16 = 20 MB

    prep_frag<<<320, 256, 0, stream>>>(W0, W1, W2, Wf);
    cin_h<<<256, 256, 0, stream>>>(inp, Wf, pW, b0, b1);
    cin_out<<<256, 512, 0, stream>>>(Wf, pW, b0, b1, b2, out);
}

// Round 8
// 136.079 us; speedup vs baseline: 1.1044x; 1.1044x over previous
//
#include <hip/hip_runtime.h>

// xDeepFM CIN, MI355X (gfx950) — R16 resubmit (infra failed in R7, no data).
// R15 post-mortem: batch-quad = 76.6us / Mfma 27% / Occ 10% (224 VGPR, 1
// wave/SIMD). ILP-window theory falsified both directions (R11 down, R15 down);
// VALU product scales WITH MFMA count so slicing can't reduce the ratio.
// R10 (2 waves/SIMD x 8-MFMA window) is the verified local optimum: restored.
// Remaining budget: total-cin_h ~74-85us every round; cin_out floors are
// ~1us MFMA + ~5-15us HBM, R13 coalescing bought 8us => cin_out likely still
// ~40us. Theory: cross-XCD pW traffic — blockIdx%8->XCD means each 32-batch
// group's p is written across ALL 8 XCD L2s; the cin_out reader is on one.
// R16: cin_h block i: xcd=i&7, batches xcd*256+(i>>3)*4 (+3) => each XCD
// writes only its own 8 groups (2.56MB < 4MB L2). cin_out block j: xcd=j&7,
// bg=xcd*8+((j>>3)>>2), region=(j>>3)&3 => group read from LOCAL L2.
// Pure index remap; arithmetic, layouts, schedules unchanged from R13.

typedef _Float16 f16;
typedef _Float16 f16x4 __attribute__((ext_vector_type(4)));
typedef _Float16 f16x8 __attribute__((ext_vector_type(8)));
typedef float f32x4 __attribute__((ext_vector_type(4)));
typedef float f32x16 __attribute__((ext_vector_type(16)));

#define HSTR 72      // h LDS row stride (f16): 144B = 9*16B, b128-aligned
#define GSTR 163840  // pW per-32-batch-group stride (f16): 320 frags * 512
#define P0G  0       // p0 frags [0,64)   within group
#define P1G  32768   // p1 frags [0,128)  within group
#define P2G  98304   // p2 frags [0,128)  within group

__device__ __forceinline__ f32x16 zero16() {
    f32x16 v;
#pragma unroll
    for (int i = 0; i < 16; ++i) v[i] = 0.0f;
    return v;
}

// ---------------- prep: W (fp32 row-major) -> f16 fragment-ordered ----------
// Fragment (mc, kk) = 512 f16; element lane*8+i =
//   W[rbase + mc*32 + (lane&31)][kk*16 + (lane>>5)*8 + i]
// Regions (f16 offsets): H0@0 (W0 r0..63, KK=64) | O0@65536 (W0 r64..127) |
// H1@131072 (W1 r0..63, KK=128) | O1@262144 (W1 r64..127) | O2@393216 (W2 all).
__global__ void __launch_bounds__(256)
prep_frag(const float* __restrict__ W0, const float* __restrict__ W1,
          const float* __restrict__ W2, f16* __restrict__ dst)
{
    int g = (blockIdx.x * 256 + threadIdx.x) * 8;    // grid = 320
    const float* src; int base, KK, rbase;
    if (g < 65536)       { src = W0; base = 0;      KK = 64;  rbase = 0;  }
    else if (g < 131072) { src = W0; base = 65536;  KK = 64;  rbase = 64; }
    else if (g < 262144) { src = W1; base = 131072; KK = 128; rbase = 0;  }
    else if (g < 393216) { src = W1; base = 262144; KK = 128; rbase = 64; }
    else                 { src = W2; base = 393216; KK = 128; rbase = 0;  }
    int local = g - base;
    int frag  = local >> 9;
    int lane  = (local >> 3) & 63;
    int kk    = frag % KK;
    int mc    = frag / KK;
    int row   = rbase + mc * 32 + (lane & 31);
    int col   = kk * 16 + (lane >> 5) * 8;
    int IC    = KK * 16;
    const float* s = src + (size_t)row * IC + col;
    f16x8 o;
#pragma unroll
    for (int i = 0; i < 8; ++i) o[i] = (f16)s[i];
    *(f16x8*)(dst + g) = o;
}

// ---- p-chunk: P rows [jb, jb+32) of one batch (M=32 j, N=32 z, K=64) ------
// Writes fragment-ordered: pdst = groupbase + regionoff + (b&31)*8.
__device__ __forceinline__ void p_chunk(const f16* __restrict__ hrows,
                                        const f16x8 (&pB)[4],
                                        f16* __restrict__ pdst, int jb,
                                        int t, int q)
{
    f32x16 acc = zero16();
#pragma unroll
    for (int s = 0; s < 4; ++s) {
        f16x8 a = *(const f16x8*)(hrows + t * HSTR + s * 16 + q * 8);
        acc = __builtin_amdgcn_mfma_f32_32x32x16_f16(a, pB[s], acc, 0, 0, 0);
    }
#pragma unroll
    for (int r = 0; r < 16; ++r) {
        int j = jb + (r & 3) + 8 * (r >> 2) + 4 * q;
        int f = j * 2 + (t >> 4);
        pdst[f * 512 + ((t >> 3) & 1) * 256 + (t & 7)] = (f16)acc[r];
    }
}

// ---- h-GEMM: rows [g*32,+32), ALL 64 cols, TWO batches ---------------------
// Per j: 2 W-frag loads feed 8 MFMAs (258 SIMD-cyc window > L2 latency).
// Ping-pong depth-2 (j, j+1 resident; refill j+2).
template <int HJ>
__device__ __forceinline__ void h_gemm4(const f16* __restrict__ Hf,
                                        const f16* __restrict__ h0,
                                        const f16* __restrict__ h1,
                                        int lane8, int t,
                                        const f16x8 (&ip)[2][2][2],   // [b][kq][nh]
                                        f32x16 (&acc)[2][2])          // [b][nh]
{
    acc[0][0] = zero16(); acc[0][1] = zero16();
    acc[1][0] = zero16(); acc[1][1] = zero16();
    const f16* Wp = Hf + lane8;
    f16x8 wf[2][2];   // [phase][kq]
    f16   sc[2][4];   // [phase][b*2+nh]
#pragma unroll
    for (int ph = 0; ph < 2; ++ph) {
        wf[ph][0] = *(const f16x8*)(Wp + (ph * 2 + 0) * 512);
        wf[ph][1] = *(const f16x8*)(Wp + (ph * 2 + 1) * 512);
        sc[ph][0] = h0[ph * HSTR + t];
        sc[ph][1] = h0[ph * HSTR + 32 + t];
        sc[ph][2] = h1[ph * HSTR + t];
        sc[ph][3] = h1[ph * HSTR + 32 + t];
    }
    for (int jj = 0; jj < HJ; jj += 2) {
#pragma unroll
        for (int ph = 0; ph < 2; ++ph) {
            f16x8 w0 = wf[ph][0], w1 = wf[ph][1];
            f16 s00 = sc[ph][0], s01 = sc[ph][1];
            f16 s10 = sc[ph][2], s11 = sc[ph][3];
            int jn = jj + ph + 2;
            if (jn > HJ - 1) jn = HJ - 1;              // clamped refill
            wf[ph][0] = *(const f16x8*)(Wp + (jn * 2 + 0) * 512);
            wf[ph][1] = *(const f16x8*)(Wp + (jn * 2 + 1) * 512);
            sc[ph][0] = h0[jn * HSTR + t];
            sc[ph][1] = h0[jn * HSTR + 32 + t];
            sc[ph][2] = h1[jn * HSTR + t];
            sc[ph][3] = h1[jn * HSTR + 32 + t];
            acc[0][0] = __builtin_amdgcn_mfma_f32_32x32x16_f16(w0, ip[0][0][0] * s00, acc[0][0], 0, 0, 0);
            acc[0][0] = __builtin_amdgcn_mfma_f32_32x32x16_f16(w1, ip[0][1][0] * s00, acc[0][0], 0, 0, 0);
            acc[0][1] = __builtin_amdgcn_mfma_f32_32x32x16_f16(w0, ip[0][0][1] * s01, acc[0][1], 0, 0, 0);
            acc[0][1] = __builtin_amdgcn_mfma_f32_32x32x16_f16(w1, ip[0][1][1] * s01, acc[0][1], 0, 0, 0);
            acc[1][0] = __builtin_amdgcn_mfma_f32_32x32x16_f16(w0, ip[1][0][0] * s10, acc[1][0], 0, 0, 0);
            acc[1][0] = __builtin_amdgcn_mfma_f32_32x32x16_f16(w1, ip[1][1][0] * s10, acc[1][0], 0, 0, 0);
            acc[1][1] = __builtin_amdgcn_mfma_f32_32x32x16_f16(w0, ip[1][0][1] * s11, acc[1][1], 0, 0, 0);
            acc[1][1] = __builtin_amdgcn_mfma_f32_32x32x16_f16(w1, ip[1][1][1] * s11, acc[1][1], 0, 0, 0);
        }
    }
}

__device__ __forceinline__ void load_bias(const float* __restrict__ bl,
                                          float (&bve)[16], int g, int q)
{
#pragma unroll
    for (int r = 0; r < 16; ++r)
        bve[r] = bl[g * 32 + (r & 3) + 8 * (r >> 2) + 4 * q];
}

// Write h_{l+1} rows [g*32,+32), all 64 cols, both batches.
__device__ __forceinline__ void epi4(const f32x16 (&acc)[2][2],
                                     f16* __restrict__ h0d, f16* __restrict__ h1d,
                                     const float (&bve)[16], int g, int t, int q)
{
#pragma unroll
    for (int r = 0; r < 16; ++r) {
        int row = g * 32 + (r & 3) + 8 * (r >> 2) + 4 * q;
        h0d[row * HSTR + t]      = (f16)(acc[0][0][r] + bve[r]);
        h0d[row * HSTR + 32 + t] = (f16)(acc[0][1][r] + bve[r]);
        h1d[row * HSTR + t]      = (f16)(acc[1][0][r] + bve[r]);
        h1d[row * HSTR + 32 + t] = (f16)(acc[1][1][r] + bve[r]);
    }
}

// =================== Kernel 1: h-chain + p-vectors =========================
__global__ void __launch_bounds__(256, 2)
cin_h(const float* __restrict__ inp, const f16* __restrict__ Wf,
      f16* __restrict__ pW,
      const float* __restrict__ b0v, const float* __restrict__ b1v)
{
    __shared__ __attribute__((aligned(16))) f16 hL[4 * 64 * HSTR];  // 36864 B

    const int tid   = threadIdx.x;
    const int w     = tid >> 6;
    const int lane  = tid & 63;
    const int t     = lane & 31;
    const int q     = lane >> 5;
    const int lane8 = lane * 8;
    const int bp    = w & 1;          // batch-pair (local batches bp*2, bp*2+1)
    const int g     = w >> 1;         // row-half
    // XCD-aligned batch assignment: blockIdx%8 -> XCD (round-robin heuristic).
    // XCD x writes only groups 8x..8x+7 (2.56 MB, L2-resident).
    const int b0i   = (blockIdx.x & 7) * 256 + (blockIdx.x >> 3) * 4;

    // Stage: 4 batches x 32 z-rows of inp (f32 coalesced) -> hL rows 0..31.
#pragma unroll
    for (int it = 0; it < 8; ++it) {
        int idx = it * 1024 + tid * 4;
        int b = idx >> 11, rem = idx & 2047;
        int z = rem >> 6, k = rem & 63;
        f32x4 v = *(const f32x4*)(inp + (size_t)(b0i + b) * 2048 + rem);
        f16x4 h4;
        h4[0] = (f16)v[0]; h4[1] = (f16)v[1]; h4[2] = (f16)v[2]; h4[3] = (f16)v[3];
        *(f16x4*)(hL + b * 64 * HSTR + z * HSTR + k) = h4;
    }
    __syncthreads();                                   // B0: h0 (=inp) ready

    // ip[b][kq][nh][i] = inp[bp*2+b][z=kq*16+q*8+i][nh*32+t]
    f16x8 ip[2][2][2];
#pragma unroll
    for (int b = 0; b < 2; ++b) {
        const f16* src = hL + (bp * 2 + b) * 64 * HSTR;
#pragma unroll
        for (int kq = 0; kq < 2; ++kq)
#pragma unroll
            for (int nh = 0; nh < 2; ++nh) {
                f16x8 v;
#pragma unroll
                for (int i = 0; i < 8; ++i)
                    v[i] = src[(kq * 16 + q * 8 + i) * HSTR + nh * 32 + t];
                ip[b][kq][nh] = v;
            }
    }
    // pB[s][i] = inp[w][z=t][k=s*16+q*8+i] — p-GEMM B-frags (wave w <-> batch w)
    f16x8 pB[4];
#pragma unroll
    for (int s = 0; s < 4; ++s)
        pB[s] = *(const f16x8*)(hL + w * 64 * HSTR + t * HSTR + s * 16 + q * 8);

    const int bglob = b0i + w;        // wave w <-> batch w (p-work)
    f16* pG = pW + (size_t)(bglob >> 5) * GSTR + (bglob & 31) * 8;
    const f16* H0 = Wf;
    const f16* H1 = Wf + 131072;
    f16* hA = hL + (bp * 2) * 64 * HSTR;
    f16* hB = hL + (bp * 2 + 1) * 64 * HSTR;
    f32x16 acc[2][2];
    float bve[16];

    // ---- Layer 0 (HJ=32) ----
    p_chunk(hL + w * 64 * HSTR, pB, pG + P0G, 0, t, q);     // p0 j 0..31
    h_gemm4<32>(H0 + g * 64 * 512, hA, hB, lane8, t, ip, acc);
    load_bias(b0v, bve, g, q);
    __syncthreads();                                   // B1: all h0 reads done
    epi4(acc, hA, hB, bve, g, t, q);                   // h1 (rows 0..63)
    __syncthreads();                                   // B2: h1 ready

    // ---- Layer 1 (HJ=64) ----
    p_chunk(hL + w * 64 * HSTR,             pB, pG + P1G, 0,  t, q);
    p_chunk(hL + w * 64 * HSTR + 32 * HSTR, pB, pG + P1G, 32, t, q);
    h_gemm4<64>(H1 + g * 128 * 512, hA, hB, lane8, t, ip, acc);
    load_bias(b1v, bve, g, q);
    __syncthreads();                                   // B3: all h1 reads done
    epi4(acc, hA, hB, bve, g, t, q);                   // h1 -> h2 in place
    __syncthreads();                                   // B4: h2 ready

    p_chunk(hL + w * 64 * HSTR,             pB, pG + P2G, 0,  t, q);
    p_chunk(hL + w * 64 * HSTR + 32 * HSTR, pB, pG + P2G, 32, t, q);
}

// =================== Kernel 2: out GEMMs (N = batch), R13 ==================
// Block = 512 thr (8 waves): mi = M-half, ki = K-quarter. B-frags 1KB
// wave-coalesced (fragment-ordered pW); mi-pair reads identical addresses
// (L1 share). Depth-8 prefetch ring. 4-way K partials reduced via 32KB LDS.
template <int KK>   // KK = total K-fragments (region0: 64, others: 128)
__device__ __forceinline__ void o_tile(const f16* __restrict__ Of,
                                       const f16* __restrict__ pBase,
                                       const float* __restrict__ biasp,
                                       float* __restrict__ out,
                                       float* __restrict__ rP,
                                       int bg, int colbase, int tid)
{
    const int w = tid >> 6, lane = tid & 63, t = lane & 31, q = lane >> 5;
    const int lane8 = lane * 8;
    const int mi = w & 1, ki = w >> 1;           // mi pairs adjacent -> B share
    const int SQ = KK / 4;                       // K-frags per wave (16 or 32)
    const f16* Ap = Of + (size_t)(mi * KK + ki * SQ) * 512 + lane8;
    const f16* Bp = pBase + (size_t)(ki * SQ) * 512 + lane8;

    f32x16 acc = zero16();
    f16x8 af[8], bf[8];
#pragma unroll
    for (int i = 0; i < 8; ++i) {
        af[i] = *(const f16x8*)(Ap + i * 512);
        bf[i] = *(const f16x8*)(Bp + i * 512);
    }
#pragma unroll 8
    for (int s = 0; s < SQ; ++s) {
        int idx = s & 7;
        f16x8 a = af[idx], b = bf[idx];
        int sn = s + 8 < SQ ? s + 8 : SQ - 1;    // clamped refill
        af[idx] = *(const f16x8*)(Ap + sn * 512);
        bf[idx] = *(const f16x8*)(Bp + sn * 512);
        acc = __builtin_amdgcn_mfma_f32_32x32x16_f16(a, b, acc, 0, 0, 0);
    }
#pragma unroll
    for (int r = 0; r < 16; ++r) {
        int m = mi * 32 + (r & 3) + 8 * (r >> 2) + 4 * q;
        rP[(ki * 32 + t) * 64 + m] = acc[r];
    }
    __syncthreads();
    // Combine: 512 thr x f32x4 = 2048 f32 (32 batches x 64 cols).
    {
        int n = tid >> 4;            // batch row 0..31
        int o = (tid & 15) * 4;      // col 0..60
        f32x4 v = *(const f32x4*)(rP + n * 64 + o);
#pragma unroll
        for (int k2 = 1; k2 < 4; ++k2) {
            f32x4 u = *(const f32x4*)(rP + (k2 * 32 + n) * 64 + o);
            v[0] += u[0]; v[1] += u[1]; v[2] += u[2]; v[3] += u[3];
        }
        f32x4 bb = *(const f32x4*)(biasp + o);
        v[0] += 64.0f * bb[0]; v[1] += 64.0f * bb[1];
        v[2] += 64.0f * bb[2]; v[3] += 64.0f * bb[3];
        *(f32x4*)(out + (size_t)(bg * 32 + n) * 256 + colbase + o) = v;
    }
}

__global__ void __launch_bounds__(512, 2)
cin_out(const f16* __restrict__ Wf, const f16* __restrict__ pW,
        const float* __restrict__ b0v, const float* __restrict__ b1v,
        const float* __restrict__ b2v, float* __restrict__ out)
{
    __shared__ __attribute__((aligned(16))) float rP[4 * 32 * 64];  // 32 KB
    const int tid = threadIdx.x;
    // XCD-aligned: block j on XCD j%8 reads group bg = (j%8)*8 + ... which
    // was written by cin_h blocks on the SAME XCD (local L2 hit).
    const int xcd = blockIdx.x & 7;
    const int n   = blockIdx.x >> 3;          // 0..31
    const int bg  = xcd * 8 + (n >> 2);       // 32-batch group
    const int r   = n & 3;                    // region
    const f16* pGrp = pW + (size_t)bg * GSTR;
    if (r == 0)
        o_tile<64> (Wf + 65536,  pGrp + P0G, b0v + 64, out, rP, bg, 0,   tid);
    else if (r == 1)
        o_tile<128>(Wf + 262144, pGrp + P1G, b1v + 64, out, rP, bg, 64,  tid);
    else if (r == 2)
        o_tile<128>(Wf + 393216, pGrp + P2G, b2v,      out, rP, bg, 128, tid);
    else
        o_tile<128>(Wf + 524288, pGrp + P2G, b2v + 64, out, rP, bg, 192, tid);
}

extern "C" void kernel_launch(void* const* d_in, const int* in_sizes, int n_in,
                              void* d_out, int out_size, void* d_ws, size_t ws_size,
                              hipStream_t stream)
{
    const float* inp = (const float*)d_in[0];
    const float* W0  = (const float*)d_in[1];
    const float* b0  = (const float*)d_in[2];
    const float* W1  = (const float*)d_in[3];
    const float* b1  = (const float*)d_in[4];
    const float* W2  = (const float*)d_in[5];
    const float* b2  = (const float*)d_in[6];
    float* out = (float*)d_out;

    f16* Wf = (f16*)d_ws;             // 655360 f16 = 1.25 MB fragment-ordered
    f16* pW = Wf + 655360;            // 64 groups * 163840 f16 = 20 MB

    prep_frag<<<320, 256, 0, stream>>>(W0, W1, W2, Wf);
    cin_h<<<512, 256, 0, stream>>>(inp, Wf, pW, b0, b1);
    cin_out<<<256, 512, 0, stream>>>(Wf, pW, b0, b1, b2, out);
}

// Round 9
// 132.273 us; speedup vs baseline: 1.1362x; 1.0288x over previous
//
#include <hip/hip_runtime.h>

// xDeepFM CIN, MI355X (gfx950) — R17.
// R16 post-mortem: XCD remap NULL (total 136.1 vs R13 132.3) and cin_h
// regressed +4us from the remap => reverted to R13 exact. Ledger: only
// cin_out change that helped = R13 B-coalescing (-8us); occupancy-in-block
// (R12) neutral (kept 2 waves/SIMD); XCD remap null.
// Residual ~76us theory: cin_out reads ~20MB fresh pW at L3/HBM latency
// (~600-900cyc); depth-8 ring = 258-cyc window covers L2 only; 2 waves/SIMD
// can't TLP-hide the rest. R17 cin_out: 1024-thr blocks, 8-way K-split =
// 16 waves = 4 waves/SIMD (2x TLP), rP 64KB LDS, 8-partial combine.
// cin_h/prep/pW layout: R13 verbatim.

typedef _Float16 f16;
typedef _Float16 f16x4 __attribute__((ext_vector_type(4)));
typedef _Float16 f16x8 __attribute__((ext_vector_type(8)));
typedef float f32x4 __attribute__((ext_vector_type(4)));
typedef float f32x16 __attribute__((ext_vector_type(16)));

#define HSTR 72      // h LDS row stride (f16): 144B = 9*16B, b128-aligned
#define GSTR 163840  // pW per-32-batch-group stride (f16): 320 frags * 512
#define P0G  0       // p0 frags [0,64)   within group
#define P1G  32768   // p1 frags [0,128)  within group
#define P2G  98304   // p2 frags [0,128)  within group

__device__ __forceinline__ f32x16 zero16() {
    f32x16 v;
#pragma unroll
    for (int i = 0; i < 16; ++i) v[i] = 0.0f;
    return v;
}

// ---------------- prep: W (fp32 row-major) -> f16 fragment-ordered ----------
// Fragment (mc, kk) = 512 f16; element lane*8+i =
//   W[rbase + mc*32 + (lane&31)][kk*16 + (lane>>5)*8 + i]
// Regions (f16 offsets): H0@0 (W0 r0..63, KK=64) | O0@65536 (W0 r64..127) |
// H1@131072 (W1 r0..63, KK=128) | O1@262144 (W1 r64..127) | O2@393216 (W2 all).
__global__ void __launch_bounds__(256)
prep_frag(const float* __restrict__ W0, const float* __restrict__ W1,
          const float* __restrict__ W2, f16* __restrict__ dst)
{
    int g = (blockIdx.x * 256 + threadIdx.x) * 8;    // grid = 320
    const float* src; int base, KK, rbase;
    if (g < 65536)       { src = W0; base = 0;      KK = 64;  rbase = 0;  }
    else if (g < 131072) { src = W0; base = 65536;  KK = 64;  rbase = 64; }
    else if (g < 262144) { src = W1; base = 131072; KK = 128; rbase = 0;  }
    else if (g < 393216) { src = W1; base = 262144; KK = 128; rbase = 64; }
    else                 { src = W2; base = 393216; KK = 128; rbase = 0;  }
    int local = g - base;
    int frag  = local >> 9;
    int lane  = (local >> 3) & 63;
    int kk    = frag % KK;
    int mc    = frag / KK;
    int row   = rbase + mc * 32 + (lane & 31);
    int col   = kk * 16 + (lane >> 5) * 8;
    int IC    = KK * 16;
    const float* s = src + (size_t)row * IC + col;
    f16x8 o;
#pragma unroll
    for (int i = 0; i < 8; ++i) o[i] = (f16)s[i];
    *(f16x8*)(dst + g) = o;
}

// ---- p-chunk: P rows [jb, jb+32) of one batch (M=32 j, N=32 z, K=64) ------
// Writes fragment-ordered: pdst = groupbase + regionoff + (b&31)*8.
__device__ __forceinline__ void p_chunk(const f16* __restrict__ hrows,
                                        const f16x8 (&pB)[4],
                                        f16* __restrict__ pdst, int jb,
                                        int t, int q)
{
    f32x16 acc = zero16();
#pragma unroll
    for (int s = 0; s < 4; ++s) {
        f16x8 a = *(const f16x8*)(hrows + t * HSTR + s * 16 + q * 8);
        acc = __builtin_amdgcn_mfma_f32_32x32x16_f16(a, pB[s], acc, 0, 0, 0);
    }
#pragma unroll
    for (int r = 0; r < 16; ++r) {
        int j = jb + (r & 3) + 8 * (r >> 2) + 4 * q;
        int f = j * 2 + (t >> 4);
        pdst[f * 512 + ((t >> 3) & 1) * 256 + (t & 7)] = (f16)acc[r];
    }
}

// ---- h-GEMM: rows [g*32,+32), ALL 64 cols, TWO batches ---------------------
// Per j: 2 W-frag loads feed 8 MFMAs (258 SIMD-cyc window > L2 latency).
// Ping-pong depth-2 (j, j+1 resident; refill j+2).
template <int HJ>
__device__ __forceinline__ void h_gemm4(const f16* __restrict__ Hf,
                                        const f16* __restrict__ h0,
                                        const f16* __restrict__ h1,
                                        int lane8, int t,
                                        const f16x8 (&ip)[2][2][2],   // [b][kq][nh]
                                        f32x16 (&acc)[2][2])          // [b][nh]
{
    acc[0][0] = zero16(); acc[0][1] = zero16();
    acc[1][0] = zero16(); acc[1][1] = zero16();
    const f16* Wp = Hf + lane8;
    f16x8 wf[2][2];   // [phase][kq]
    f16   sc[2][4];   // [phase][b*2+nh]
#pragma unroll
    for (int ph = 0; ph < 2; ++ph) {
        wf[ph][0] = *(const f16x8*)(Wp + (ph * 2 + 0) * 512);
        wf[ph][1] = *(const f16x8*)(Wp + (ph * 2 + 1) * 512);
        sc[ph][0] = h0[ph * HSTR + t];
        sc[ph][1] = h0[ph * HSTR + 32 + t];
        sc[ph][2] = h1[ph * HSTR + t];
        sc[ph][3] = h1[ph * HSTR + 32 + t];
    }
    for (int jj = 0; jj < HJ; jj += 2) {
#pragma unroll
        for (int ph = 0; ph < 2; ++ph) {
            f16x8 w0 = wf[ph][0], w1 = wf[ph][1];
            f16 s00 = sc[ph][0], s01 = sc[ph][1];
            f16 s10 = sc[ph][2], s11 = sc[ph][3];
            int jn = jj + ph + 2;
            if (jn > HJ - 1) jn = HJ - 1;              // clamped refill
            wf[ph][0] = *(const f16x8*)(Wp + (jn * 2 + 0) * 512);
            wf[ph][1] = *(const f16x8*)(Wp + (jn * 2 + 1) * 512);
            sc[ph][0] = h0[jn * HSTR + t];
            sc[ph][1] = h0[jn * HSTR + 32 + t];
            sc[ph][2] = h1[jn * HSTR + t];
            sc[ph][3] = h1[jn * HSTR + 32 + t];
            acc[0][0] = __builtin_amdgcn_mfma_f32_32x32x16_f16(w0, ip[0][0][0] * s00, acc[0][0], 0, 0, 0);
            acc[0][0] = __builtin_amdgcn_mfma_f32_32x32x16_f16(w1, ip[0][1][0] * s00, acc[0][0], 0, 0, 0);
            acc[0][1] = __builtin_amdgcn_mfma_f32_32x32x16_f16(w0, ip[0][0][1] * s01, acc[0][1], 0, 0, 0);
            acc[0][1] = __builtin_amdgcn_mfma_f32_32x32x16_f16(w1, ip[0][1][1] * s01, acc[0][1], 0, 0, 0);
            acc[1][0] = __builtin_amdgcn_mfma_f32_32x32x16_f16(w0, ip[1][0][0] * s10, acc[1][0], 0, 0, 0);
            acc[1][0] = __builtin_amdgcn_mfma_f32_32x32x16_f16(w1, ip[1][1][0] * s10, acc[1][0], 0, 0, 0);
            acc[1][1] = __builtin_amdgcn_mfma_f32_32x32x16_f16(w0, ip[1][0][1] * s11, acc[1][1], 0, 0, 0);
            acc[1][1] = __builtin_amdgcn_mfma_f32_32x32x16_f16(w1, ip[1][1][1] * s11, acc[1][1], 0, 0, 0);
        }
    }
}

__device__ __forceinline__ void load_bias(const float* __restrict__ bl,
                                          float (&bve)[16], int g, int q)
{
#pragma unroll
    for (int r = 0; r < 16; ++r)
        bve[r] = bl[g * 32 + (r & 3) + 8 * (r >> 2) + 4 * q];
}

// Write h_{l+1} rows [g*32,+32), all 64 cols, both batches.
__device__ __forceinline__ void epi4(const f32x16 (&acc)[2][2],
                                     f16* __restrict__ h0d, f16* __restrict__ h1d,
                                     const float (&bve)[16], int g, int t, int q)
{
#pragma unroll
    for (int r = 0; r < 16; ++r) {
        int row = g * 32 + (r & 3) + 8 * (r >> 2) + 4 * q;
        h0d[row * HSTR + t]      = (f16)(acc[0][0][r] + bve[r]);
        h0d[row * HSTR + 32 + t] = (f16)(acc[0][1][r] + bve[r]);
        h1d[row * HSTR + t]      = (f16)(acc[1][0][r] + bve[r]);
        h1d[row * HSTR + 32 + t] = (f16)(acc[1][1][r] + bve[r]);
    }
}

// =================== Kernel 1: h-chain + p-vectors (R13 verbatim) ==========
__global__ void __launch_bounds__(256, 2)
cin_h(const float* __restrict__ inp, const f16* __restrict__ Wf,
      f16* __restrict__ pW,
      const float* __restrict__ b0v, const float* __restrict__ b1v)
{
    __shared__ __attribute__((aligned(16))) f16 hL[4 * 64 * HSTR];  // 36864 B

    const int tid   = threadIdx.x;
    const int w     = tid >> 6;
    const int lane  = tid & 63;
    const int t     = lane & 31;
    const int q     = lane >> 5;
    const int lane8 = lane * 8;
    const int bp    = w & 1;          // batch-pair (local batches bp*2, bp*2+1)
    const int g     = w >> 1;         // row-half
    const int b0i   = blockIdx.x * 4;

    // Stage: 4 batches x 32 z-rows of inp (f32 coalesced) -> hL rows 0..31.
#pragma unroll
    for (int it = 0; it < 8; ++it) {
        int idx = it * 1024 + tid * 4;
        int b = idx >> 11, rem = idx & 2047;
        int z = rem >> 6, k = rem & 63;
        f32x4 v = *(const f32x4*)(inp + (size_t)(b0i + b) * 2048 + rem);
        f16x4 h4;
        h4[0] = (f16)v[0]; h4[1] = (f16)v[1]; h4[2] = (f16)v[2]; h4[3] = (f16)v[3];
        *(f16x4*)(hL + b * 64 * HSTR + z * HSTR + k) = h4;
    }
    __syncthreads();                                   // B0: h0 (=inp) ready

    // ip[b][kq][nh][i] = inp[bp*2+b][z=kq*16+q*8+i][nh*32+t]
    f16x8 ip[2][2][2];
#pragma unroll
    for (int b = 0; b < 2; ++b) {
        const f16* src = hL + (bp * 2 + b) * 64 * HSTR;
#pragma unroll
        for (int kq = 0; kq < 2; ++kq)
#pragma unroll
            for (int nh = 0; nh < 2; ++nh) {
                f16x8 v;
#pragma unroll
                for (int i = 0; i < 8; ++i)
                    v[i] = src[(kq * 16 + q * 8 + i) * HSTR + nh * 32 + t];
                ip[b][kq][nh] = v;
            }
    }
    // pB[s][i] = inp[w][z=t][k=s*16+q*8+i] — p-GEMM B-frags (wave w <-> batch w)
    f16x8 pB[4];
#pragma unroll
    for (int s = 0; s < 4; ++s)
        pB[s] = *(const f16x8*)(hL + w * 64 * HSTR + t * HSTR + s * 16 + q * 8);

    const int bglob = b0i + w;        // wave w <-> batch w (p-work)
    f16* pG = pW + (size_t)(bglob >> 5) * GSTR + (bglob & 31) * 8;
    const f16* H0 = Wf;
    const f16* H1 = Wf + 131072;
    f16* hA = hL + (bp * 2) * 64 * HSTR;
    f16* hB = hL + (bp * 2 + 1) * 64 * HSTR;
    f32x16 acc[2][2];
    float bve[16];

    // ---- Layer 0 (HJ=32) ----
    p_chunk(hL + w * 64 * HSTR, pB, pG + P0G, 0, t, q);     // p0 j 0..31
    h_gemm4<32>(H0 + g * 64 * 512, hA, hB, lane8, t, ip, acc);
    load_bias(b0v, bve, g, q);
    __syncthreads();                                   // B1: all h0 reads done
    epi4(acc, hA, hB, bve, g, t, q);                   // h1 (rows 0..63)
    __syncthreads();                                   // B2: h1 ready

    // ---- Layer 1 (HJ=64) ----
    p_chunk(hL + w * 64 * HSTR,             pB, pG + P1G, 0,  t, q);
    p_chunk(hL + w * 64 * HSTR + 32 * HSTR, pB, pG + P1G, 32, t, q);
    h_gemm4<64>(H1 + g * 128 * 512, hA, hB, lane8, t, ip, acc);
    load_bias(b1v, bve, g, q);
    __syncthreads();                                   // B3: all h1 reads done
    epi4(acc, hA, hB, bve, g, t, q);                   // h1 -> h2 in place
    __syncthreads();                                   // B4: h2 ready

    p_chunk(hL + w * 64 * HSTR,             pB, pG + P2G, 0,  t, q);
    p_chunk(hL + w * 64 * HSTR + 32 * HSTR, pB, pG + P2G, 32, t, q);
}

// =================== Kernel 2: out GEMMs (N = batch), R17 ==================
// Block = 1024 thr (16 waves = 4 waves/SIMD): mi = M-half, ki = K-eighth.
// 2x per-SIMD TLP vs R13 to hide L3/HBM latency on the fresh-pW stream.
// B-frags 1KB wave-coalesced; mi-pair shares B addresses (L1 hit).
// Depth-8 prefetch ring. 8-way K partials reduced via 64KB LDS.
template <int KK>   // KK = total K-fragments (region0: 64, others: 128)
__device__ __forceinline__ void o_tile(const f16* __restrict__ Of,
                                       const f16* __restrict__ pBase,
                                       const float* __restrict__ biasp,
                                       float* __restrict__ out,
                                       float* __restrict__ rP,
                                       int bg, int colbase, int tid)
{
    const int w = tid >> 6, lane = tid & 63, t = lane & 31, q = lane >> 5;
    const int lane8 = lane * 8;
    const int mi = w & 1, ki = w >> 1;           // ki = K-eighth (0..7)
    const int SQ = KK / 8;                       // K-frags per wave (8 or 16)
    const f16* Ap = Of + (size_t)(mi * KK + ki * SQ) * 512 + lane8;
    const f16* Bp = pBase + (size_t)(ki * SQ) * 512 + lane8;

    f32x16 acc = zero16();
    f16x8 af[8], bf[8];
#pragma unroll
    for (int i = 0; i < 8; ++i) {
        af[i] = *(const f16x8*)(Ap + i * 512);
        bf[i] = *(const f16x8*)(Bp + i * 512);
    }
#pragma unroll 8
    for (int s = 0; s < SQ; ++s) {
        int idx = s & 7;
        f16x8 a = af[idx], b = bf[idx];
        int sn = s + 8 < SQ ? s + 8 : SQ - 1;    // clamped refill
        af[idx] = *(const f16x8*)(Ap + sn * 512);
        bf[idx] = *(const f16x8*)(Bp + sn * 512);
        acc = __builtin_amdgcn_mfma_f32_32x32x16_f16(a, b, acc, 0, 0, 0);
    }
#pragma unroll
    for (int r = 0; r < 16; ++r) {
        int m = mi * 32 + (r & 3) + 8 * (r >> 2) + 4 * q;
        rP[(ki * 32 + t) * 64 + m] = acc[r];
    }
    __syncthreads();
    // Combine: 1024 thr x 2 cols = 2048 f32 (32 batches x 64 cols), 8 partials.
    {
        int n = tid >> 5;            // batch row 0..31
        int o = (tid & 31) * 2;      // col 0..62
        float v0 = 0.0f, v1 = 0.0f;
#pragma unroll
        for (int k2 = 0; k2 < 8; ++k2) {
            v0 += rP[(k2 * 32 + n) * 64 + o];
            v1 += rP[(k2 * 32 + n) * 64 + o + 1];
        }
        float* op = out + (size_t)(bg * 32 + n) * 256 + colbase + o;
        op[0] = v0 + 64.0f * biasp[o];
        op[1] = v1 + 64.0f * biasp[o + 1];
    }
}

__global__ void __launch_bounds__(1024, 1)
cin_out(const f16* __restrict__ Wf, const f16* __restrict__ pW,
        const float* __restrict__ b0v, const float* __restrict__ b1v,
        const float* __restrict__ b2v, float* __restrict__ out)
{
    __shared__ __attribute__((aligned(16))) float rP[8 * 32 * 64];  // 64 KB
    const int tid = threadIdx.x;
    const int r  = blockIdx.x & 3;      // region
    const int bg = blockIdx.x >> 2;     // 32-batch group (64 of them)
    const f16* pGrp = pW + (size_t)bg * GSTR;
    if (r == 0)
        o_tile<64> (Wf + 65536,  pGrp + P0G, b0v + 64, out, rP, bg, 0,   tid);
    else if (r == 1)
        o_tile<128>(Wf + 262144, pGrp + P1G, b1v + 64, out, rP, bg, 64,  tid);
    else if (r == 2)
        o_tile<128>(Wf + 393216, pGrp + P2G, b2v,      out, rP, bg, 128, tid);
    else
        o_tile<128>(Wf + 524288, pGrp + P2G, b2v + 64, out, rP, bg, 192, tid);
}

extern "C" void kernel_launch(void* const* d_in, const int* in_sizes, int n_in,
                              void* d_out, int out_size, void* d_ws, size_t ws_size,
                              hipStream_t stream)
{
    const float* inp = (const float*)d_in[0];
    const float* W0  = (const float*)d_in[1];
    const float* b0  = (const float*)d_in[2];
    const float* W1  = (const float*)d_in[3];
    const float* b1  = (const float*)d_in[4];
    const float* W2  = (const float*)d_in[5];
    const float* b2  = (const float*)d_in[6];
    float* out = (float*)d_out;

    f16* Wf = (f16*)d_ws;             // 655360 f16 = 1.25 MB fragment-ordered
    f16* pW = Wf + 655360;            // 64 groups * 163840 f16 = 20 MB

    prep_frag<<<320, 256, 0, stream>>>(W0, W1, W2, Wf);
    cin_h<<<512, 256, 0, stream>>>(inp, Wf, pW, b0, b1);
    cin_out<<<256, 1024, 0, stream>>>(Wf, pW, b0, b1, b2, out);
}